// Round 15
// baseline (118.646 us; speedup 1.0000x reference)
//
#include <hip/hip_runtime.h>
#include <math.h>

#define B_    8
#define Q_    900
#define NCLS_ 11
#define NANC_ 100
#define H_    200
#define W_    200
#define C_    256
#define HHALF 100
#define CHNK_ 113           // rank chunk per block in topk
#define CHEV_ 16            // events per staged chunk (16 KB per buffer)
#define EVSTR_ 224          // per-row event stride in ws (ints); ne <= 200

typedef float f32x4_ __attribute__((ext_vector_type(4)));

// ---------------------------------------------------------------------------
// Kernel 1: scores + rank + box transform (R12, proven).
// ---------------------------------------------------------------------------
__global__ __launch_bounds__(128) void segdet_topk_kernel(
    const float* __restrict__ pred_boxes,
    const float* __restrict__ pred_logits,
    const float* __restrict__ view,
    int*  __restrict__ ws_idx,
    int4* __restrict__ ws_box)
{
    const int b     = blockIdx.x >> 3;
    const int chunk = blockIdx.x & 7;
    const int tid   = threadIdx.x;

    __shared__ __align__(16) float sc[Q_];

    for (int q2 = tid; q2 < Q_; q2 += 128) {
        const float* l = pred_logits + (b * Q_ + q2) * NCLS_;
        float v[NCLS_];
        float m = -INFINITY;
        #pragma unroll
        for (int i = 0; i < NCLS_; ++i) { v[i] = l[i]; m = fmaxf(m, v[i]); }
        float s = 0.0f, e10 = -INFINITY;
        #pragma unroll
        for (int i = 0; i < NCLS_; ++i) {
            float e = expf(v[i] - m);
            s += e;
            if (i < NCLS_ - 1) e10 = fmaxf(e10, e);
        }
        sc[q2] = e10 / s;
    }
    __syncthreads();

    const int q = chunk * CHNK_ + tid;
    if (tid < CHNK_ && q < Q_) {
        const float my = sc[q];
        int rank = 0;
        #pragma unroll 4
        for (int j4 = 0; j4 < Q_ / 4; ++j4) {
            const float4 o = *(const float4*)&sc[j4 * 4];
            const int j = j4 * 4;
            rank += (o.x > my) || (o.x == my && (j + 0) < q);
            rank += (o.y > my) || (o.y == my && (j + 1) < q);
            rank += (o.z > my) || (o.z == my && (j + 2) < q);
            rank += (o.w > my) || (o.w == my && (j + 3) < q);
        }
        if (rank < NANC_) {
            const float* bx = pred_boxes + (b * Q_ + q) * 4;
            double cx = (double)bx[0], cy = (double)bx[1];
            double w  = exp((double)bx[2]);
            double h  = exp((double)bx[3]);
            double p[5] = { cx - 0.5 * w, cy - 0.5 * h,
                            cx + 0.5 * w, cy + 0.5 * h, 1.0 };
            const float* v5 = view + b * 25;
            int ico[4];
            #pragma unroll
            for (int i = 0; i < 4; ++i) {
                double acc = 0.0;
                #pragma unroll
                for (int j = 0; j < 5; ++j) acc += (double)v5[i * 5 + j] * p[j];
                ico[i] = (int)acc;
            }
            int x0 = min(max(ico[0], 0), W_);
            int y0 = min(max(ico[1], 0), H_);
            int x1 = min(max(ico[2], 0), W_);
            int y1 = min(max(ico[3], 0), H_);
            const int slot = b * NANC_ + rank;
            ws_idx[slot] = q;
            ws_box[slot] = make_int4(x0, y0, x1, y1);
        }
    }
}

__device__ __forceinline__ void nt_store4(float* p, f32x4_ v) {
    __builtin_nontemporal_store(v, (f32x4_*)p);
}

__device__ __forceinline__ void gload_lds_16(const float* g, float* l) {
    __builtin_amdgcn_global_load_lds(
        (const __attribute__((address_space(1))) void*)g,
        (__attribute__((address_space(3))) void*)l,
        16, 0, 0);
}

// ---------------------------------------------------------------------------
// Kernel 2 (row-prep, extended): per-row sorted event list + mask + MID STATE:
//   acc_mid[rid][256] = k-order feature sum of boxes covering pixel 100
//   hdr[rid] = (ne, ne_lo0 = #events pix<100, ne_lo1 = #events pix<=100, cnt_mid)
// Events at pix==100 are folded into acc_mid (same semantics as R8's proven
// upper-half init). 4 rows/block, per-pixel scatter (k-order), 2 barriers.
// ---------------------------------------------------------------------------
__global__ __launch_bounds__(1024) void segdet_prep_kernel(
    const float* __restrict__ box_feats,
    const int*   __restrict__ ws_idx,
    const int4*  __restrict__ ws_box,
    int*   __restrict__ g_hdr,              // [1600][4]
    int*   __restrict__ g_ev,               // [1600][EVSTR_]
    float* __restrict__ acc_mid,            // [1600][C_]
    float* __restrict__ mask)
{
    const int sub = threadIdx.x >> 8;
    const int t   = threadIdx.x & 255;
    const int ln  = threadIdx.x & 63;
    const int wv2 = (threadIdx.x >> 6) & 3;
    const int rid = blockIdx.x * 4 + sub;
    const int b   = rid / H_;
    const int h   = rid % H_;

    __shared__ __align__(16) int s_box[4][104];
    __shared__ int s_na[4];
    __shared__ int s_ws[4][4];

    if (wv2 == 0) {
        int na = 0;
        #pragma unroll
        for (int it = 0; it < 2; ++it) {
            int k = it * 64 + ln;
            bool act = false; int packed = 0;
            if (k < NANC_) {
                int4 bx = ws_box[b * NANC_ + k];
                int qi  = ws_idx[b * NANC_ + k];
                act = (bx.y <= h) && (h < bx.w) && (bx.x < bx.z);
                packed = bx.x | (bx.z << 8) | (qi << 16);
            }
            unsigned long long ball = __ballot(act);
            int pos = na + (int)__popcll(ball & ((1ull << ln) - 1ull));
            if (act) s_box[sub][pos] = packed;
            na += (int)__popcll(ball);
        }
        for (int idx = na + ln; idx < 104; idx += 64)
            s_box[sub][idx] = 0xFFFF;          // pad: x0=255 (never matches)
        if (ln == 0) s_na[sub] = na;
    }
    __syncthreads();                           // B1

    const int nact = s_na[sub];
    const int nk4  = (nact + 3) >> 2;

    // ---- per-pixel open/close counts + coverage (mask)
    int nopen = 0, ncl = 0, cov = 0;
#define CNT1_(PK) { const int x0_ = (PK) & 0xFF, x1_ = ((PK) >> 8) & 0xFF;    \
        nopen += (x0_ == t); ncl += (x1_ == t);                               \
        cov   += (x0_ <= t) && (t < x1_); }
    if (t < W_) {
        for (int k4 = 0; k4 < nk4; ++k4) {
            const int4 p4 = *(const int4*)&s_box[sub][k4 * 4];
            CNT1_(p4.x); CNT1_(p4.y); CNT1_(p4.z); CNT1_(p4.w);
        }
        mask[(size_t)rid * W_ + t] = (cov > 0) ? 1.0f : 0.0f;
    }
#undef CNT1_
    const int ntot = nopen + ncl;

    // ---- shuffle scan + cross-wave combine within group
    int incl = ntot;
    #pragma unroll
    for (int d = 1; d < 64; d <<= 1) {
        int u = __shfl_up(incl, d);
        incl = (ln >= d) ? incl + u : incl;
    }
    if (ln == 63) s_ws[sub][wv2] = incl;
    __syncthreads();                           // B2

    int prev = 0;
    #pragma unroll
    for (int j = 0; j < 4; ++j) prev += (j < wv2) ? s_ws[sub][j] : 0;
    const int ne  = s_ws[sub][0] + s_ws[sub][1] + s_ws[sub][2] + s_ws[sub][3];
    const int ofs = prev + incl - ntot;

    // ---- per-pixel scatter: opens (k-order) then closes (k-order)
    if (t < W_ && ntot > 0) {
        int po = ofs, pc = ofs + nopen;
        int* dst = g_ev + (size_t)rid * EVSTR_;
#define SCT1_(PK) { const int x0_ = (PK) & 0xFF, x1_ = ((PK) >> 8) & 0xFF;    \
        const int q_ = (PK) >> 16;                                            \
        if (x0_ == t) dst[po++] = q_ | (t << 10);                             \
        if (x1_ == t) dst[pc++] = (int)((unsigned)q_ | ((unsigned)t << 10)    \
                                         | 0x80000000u); }
        for (int k4 = 0; k4 < nk4; ++k4) {
            const int4 p4 = *(const int4*)&s_box[sub][k4 * 4];
            SCT1_(p4.x); SCT1_(p4.y); SCT1_(p4.z); SCT1_(p4.w);
        }
#undef SCT1_
    }

    // ---- mid-pixel state: k-order feature sum over boxes covering pixel 100
    float accm = 0.0f;
    int cm = 0;
    for (int k4 = 0; k4 < nk4; ++k4) {
        const int4 p4 = *(const int4*)&s_box[sub][k4 * 4];
#define MID1_(PK) { const int x0_ = (PK) & 0xFF, x1_ = ((PK) >> 8) & 0xFF;    \
        if (x0_ <= HHALF && HHALF < x1_) {                                    \
            accm += box_feats[((size_t)b * Q_ + ((PK) >> 16)) * C_ + t];      \
            ++cm; } }
        MID1_(p4.x); MID1_(p4.y); MID1_(p4.z); MID1_(p4.w);
#undef MID1_
    }
    acc_mid[(size_t)rid * C_ + t] = accm;

    if (t == 0)   { g_hdr[rid * 4 + 0] = ne; g_hdr[rid * 4 + 3] = cm; }
    if (t == 100) { g_hdr[rid * 4 + 1] = ofs;            // events pix < 100
                    g_hdr[rid * 4 + 2] = ofs + ntot; }   // events pix <= 100
}

// ---------------------------------------------------------------------------
// Kernel 3 (store-stream, half rows): 3200 blocks, each owns 100 pixels of a
// row. Lower: acc=0, events [0,ne_lo0). Upper: acc=acc_mid, cnt=cnt_mid,
// events [ne_lo1,ne). Events/block halved (fewer chunk-barrier store drains),
// 2x block parallelism keeps CU store pipes fed while heavy blocks apply
// events. Chunk-staged feature loads on lgkmcnt (R13 mechanism).
// ---------------------------------------------------------------------------
__global__ __launch_bounds__(256) void segdet_bev2_kernel(
    const float* __restrict__ box_feats,
    const int*   __restrict__ g_hdr,
    const int*   __restrict__ g_ev,
    const float* __restrict__ acc_mid,
    float* __restrict__ bev)
{
    const int bb   = blockIdx.x >> 1;
    const int seg  = blockIdx.x & 1;
    const int hidx = bb / B_;
    const int b    = bb % B_;
    const int h    = (hidx & 1) ? (HHALF - 1 - (hidx >> 1)) : (HHALF + (hidx >> 1));
    const int rid  = b * H_ + h;

    const int tid = threadIdx.x;
    const int ln  = tid & 63;
    const int wv  = tid >> 6;

    __shared__ __align__(16) float s_chunk[2][CHEV_ * C_];  // 32 KB
    __shared__ int s_e[EVSTR_];

    const int4 hd = *(const int4*)&g_hdr[rid * 4];   // ne, lo0, lo1, cnt_mid
    const int evbase = seg ? hd.z : 0;
    const int evcnt  = seg ? (hd.x - hd.z) : hd.y;
    const int segb   = seg * HHALF;

    float* obase = bev + (size_t)rid * W_ * C_ + ln * 4;

    f32x4_ acc = {0.f, 0.f, 0.f, 0.f};
    int cnt = 0;
    if (seg) {
        acc = *(const f32x4_*)&acc_mid[(size_t)rid * C_ + ln * 4];
        cnt = hd.w;
    }

    if (evcnt > 0) {
        if (tid < evcnt) s_e[tid] = g_ev[(size_t)rid * EVSTR_ + evbase + tid];
        __syncthreads();
    }

    const float* fbase = box_feats + (size_t)b * Q_ * C_ + ln * 4;
    const int nchunk = (evcnt + CHEV_ - 1) / CHEV_;

#define STAGE_(CI)                                                            \
    {                                                                         \
        const int base_ = (CI) * CHEV_;                                       \
        float* dst_ = &s_chunk[(CI) & 1][0];                                  \
        _Pragma("unroll")                                                     \
        for (int j = 0; j < 4; ++j) {                                         \
            const int e_ = base_ + wv * 4 + j;                                \
            if (e_ < evcnt) {                                                 \
                const int q_ = s_e[e_] & 0x3FF;                               \
                gload_lds_16(fbase + (size_t)q_ * C_,                         \
                             dst_ + (wv * 4 + j) * C_);                       \
            }                                                                 \
        }                                                                     \
    }

    int w = segb + wv;
    const int wend = segb + HHALF;
    if (nchunk > 0) {
        STAGE_(0);
        __syncthreads();
        for (int ci = 0; ci < nchunk; ++ci) {
            if (ci + 1 < nchunk) STAGE_(ci + 1);
            const int ebeg = ci * CHEV_;
            const int eend = (evcnt < ebeg + CHEV_) ? evcnt : (ebeg + CHEV_);
            const float* cb = &s_chunk[ci & 1][0];
            for (int e = ebeg; e < eend; ++e) {
                const int ent = s_e[e];
                const int pe  = (ent >> 10) & 0xFF;
                for (; w < pe; w += 4)
                    nt_store4(obase + (size_t)w * C_, acc);
                const f32x4_ f = *(const f32x4_*)&cb[(e - ebeg) * C_ + ln * 4];
                if (ent < 0) { acc -= f; --cnt; }
                else         { acc += f; ++cnt; }
                if (cnt == 0) acc = (f32x4_){0.f, 0.f, 0.f, 0.f};
            }
            __syncthreads();
        }
    } else if (cnt == 0) {
        acc = (f32x4_){0.f, 0.f, 0.f, 0.f};
    }
#undef STAGE_
    for (; w < wend; w += 4)
        nt_store4(obase + (size_t)w * C_, acc);
}

// ---------------------------------------------------------------------------
// Fallback bev kernel (R13, proven 101us) — if ws_size too small.
// ---------------------------------------------------------------------------
__global__ __launch_bounds__(256) void segdet_bev_kernel(
    const float* __restrict__ box_feats,
    const int*   __restrict__ ws_idx,
    const int4*  __restrict__ ws_box,
    float* __restrict__ bev,
    float* __restrict__ mask)
{
    const int hidx = blockIdx.x / B_;
    const int b    = blockIdx.x % B_;
    const int h    = (hidx & 1) ? (HHALF - 1 - (hidx >> 1)) : (HHALF + (hidx >> 1));

    const int tid = threadIdx.x;
    const int ln  = tid & 63;
    const int wv  = tid >> 6;

    __shared__ __align__(16) float s_chunk[2][CHEV_ * C_];
    __shared__ int s_box[NANC_];
    __shared__ int s_nact;
    __shared__ int s_nopen[W_];
    __shared__ int s_ofs[W_ + 1];
    __shared__ int s_ent[2 * NANC_];
    __shared__ int s_wsum[4];

    if (tid < 64) {
        int na = 0;
        #pragma unroll
        for (int it = 0; it < 2; ++it) {
            int k = it * 64 + ln;
            bool act = false;
            int packed = 0;
            if (k < NANC_) {
                int4 bx = ws_box[b * NANC_ + k];
                int qi  = ws_idx[b * NANC_ + k];
                act = (bx.y <= h) && (h < bx.w) && (bx.x < bx.z);
                packed = bx.x | (bx.z << 8) | (qi << 16);
            }
            unsigned long long ball = __ballot(act);
            int pos = na + (int)__popcll(ball & ((1ull << ln) - 1ull));
            if (act) s_box[pos] = packed;
            na += (int)__popcll(ball);
        }
        if (ln == 0) s_nact = na;
    }
    __syncthreads();

    const int nact = s_nact;
    float* obase = bev + (size_t)(b * H_ + h) * W_ * C_ + ln * 4;
    float* mrow  = mask + (size_t)(b * H_ + h) * W_;

    if (nact == 0) {
        const f32x4_ z = {0.f, 0.f, 0.f, 0.f};
        for (int w = wv; w < W_; w += 4)
            nt_store4(obase + (size_t)w * C_, z);
        if (tid < W_) __builtin_nontemporal_store(0.0f, &mrow[tid]);
        return;
    }

    int ntot = 0;
    if (tid < W_) {
        int nopen = 0, nclose = 0, cov = 0;
        for (int k = 0; k < nact; ++k) {
            int pk = s_box[k];
            int x0 = pk & 0xFF, x1 = (pk >> 8) & 0xFF;
            nopen  += (x0 == tid);
            nclose += (x1 == tid);
            cov    += (x0 <= tid) && (tid < x1);
        }
        s_nopen[tid] = nopen;
        ntot = nopen + nclose;
        __builtin_nontemporal_store((cov > 0) ? 1.0f : 0.0f, &mrow[tid]);
    }

    int incl = ntot;
    #pragma unroll
    for (int d = 1; d < 64; d <<= 1) {
        int u = __shfl_up(incl, d);
        incl = (ln >= d) ? incl + u : incl;
    }
    if (ln == 63) s_wsum[wv] = incl;
    __syncthreads();

    int prev = 0;
    #pragma unroll
    for (int j = 0; j < 4; ++j) prev += (j < wv) ? s_wsum[j] : 0;
    const int ne = s_wsum[0] + s_wsum[1] + s_wsum[2] + s_wsum[3];
    if (tid < W_) s_ofs[tid] = prev + incl - ntot;
    if (tid == 0) s_ofs[W_] = ne;
    __syncthreads();

    if (tid < nact) {
        int pk = s_box[tid];
        int x0 = pk & 0xFF, x1 = (pk >> 8) & 0xFF, q = pk >> 16;
        int ro = 0, rc = 0;
        for (int j = 0; j < tid; ++j) {
            int pj = s_box[j];
            ro += ((pj & 0xFF) == x0);
            rc += (((pj >> 8) & 0xFF) == x1);
        }
        s_ent[s_ofs[x0] + ro] = q | (x0 << 10);
        if (x1 < W_)
            s_ent[s_ofs[x1] + s_nopen[x1] + rc] =
                (int)((unsigned)q | ((unsigned)x1 << 10) | 0x80000000u);
    }
    __syncthreads();

    const float* fbase = box_feats + (size_t)b * Q_ * C_ + ln * 4;
    const int nchunk = (ne + CHEV_ - 1) / CHEV_;

#define STAGE_(CI)                                                            \
    {                                                                         \
        const int base_ = (CI) * CHEV_;                                       \
        float* dst_ = &s_chunk[(CI) & 1][0];                                  \
        _Pragma("unroll")                                                     \
        for (int j = 0; j < 4; ++j) {                                         \
            const int e_ = base_ + wv * 4 + j;                                \
            if (e_ < ne) {                                                    \
                const int q_ = s_ent[e_] & 0x3FF;                             \
                gload_lds_16(fbase + (size_t)q_ * C_,                         \
                             dst_ + (wv * 4 + j) * C_);                       \
            }                                                                 \
        }                                                                     \
    }

    STAGE_(0);
    __syncthreads();

    f32x4_ acc = {0.f, 0.f, 0.f, 0.f};
    int cnt = 0;
    int w = wv;
    for (int ci = 0; ci < nchunk; ++ci) {
        if (ci + 1 < nchunk) STAGE_(ci + 1);
        const int ebeg = ci * CHEV_;
        const int eend = (ne < ebeg + CHEV_) ? ne : (ebeg + CHEV_);
        const float* cb = &s_chunk[ci & 1][0];
        for (int e = ebeg; e < eend; ++e) {
            const int ent = s_ent[e];
            const int pe  = (ent >> 10) & 0xFF;
            for (; w < pe; w += 4)
                nt_store4(obase + (size_t)w * C_, acc);
            const f32x4_ f = *(const f32x4_*)&cb[(e - ebeg) * C_ + ln * 4];
            if (ent < 0) { acc -= f; --cnt; }
            else         { acc += f; ++cnt; }
            if (cnt == 0) acc = (f32x4_){0.f, 0.f, 0.f, 0.f};
        }
        __syncthreads();
    }
#undef STAGE_
    for (; w < W_; w += 4)
        nt_store4(obase + (size_t)w * C_, acc);
}

// ---------------------------------------------------------------------------
extern "C" void kernel_launch(void* const* d_in, const int* in_sizes, int n_in,
                              void* d_out, int out_size, void* d_ws, size_t ws_size,
                              hipStream_t stream) {
    const float* pred_boxes  = (const float*)d_in[0];
    const float* pred_logits = (const float*)d_in[1];
    const float* box_feats   = (const float*)d_in[2];
    const float* view        = (const float*)d_in[3];

    float* bev  = (float*)d_out;
    float* mask = bev + (size_t)B_ * H_ * W_ * C_;

    int*   ws_idx  = (int*)d_ws;                           // @0       (3200 B)
    int4*  ws_box  = (int4*)((char*)d_ws + 3200);          // @3200    (12800 B)
    int*   g_hdr   = (int*)((char*)d_ws + 16000);          // @16000   (25600 B)
    int*   g_ev    = (int*)((char*)d_ws + 41600);          // @41600   (1433600 B)
    float* acc_mid = (float*)((char*)d_ws + 1475200);      // @1475200 (1638400 B)
    const size_t need = 1475200ull + 1638400ull;           // 3,113,600 B

    segdet_topk_kernel<<<B_ * 8, 128, 0, stream>>>(pred_boxes, pred_logits, view,
                                                   ws_idx, ws_box);
    if (ws_size >= need) {
        segdet_prep_kernel<<<(B_ * H_) / 4, 1024, 0, stream>>>(
            box_feats, ws_idx, ws_box, g_hdr, g_ev, acc_mid, mask);
        segdet_bev2_kernel<<<B_ * H_ * 2, 256, 0, stream>>>(
            box_feats, g_hdr, g_ev, acc_mid, bev);
    } else {
        segdet_bev_kernel<<<B_ * H_, 256, 0, stream>>>(
            box_feats, ws_idx, ws_box, bev, mask);
    }
}

// Round 16
// 100.608 us; speedup vs baseline: 1.1793x; 1.1793x over previous
//
#include <hip/hip_runtime.h>
#include <math.h>

#define B_    8
#define Q_    900
#define NCLS_ 11
#define NANC_ 100
#define H_    200
#define W_    200
#define C_    256
#define HHALF 100
#define CHNK_ 113           // rank chunk per block in topk
#define CHEV_ 16            // events per staged chunk (path B)
#define FCAP_ 58            // all-LDS path capacity (58 KB feats)

typedef float f32x4_ __attribute__((ext_vector_type(4)));

// ---------------------------------------------------------------------------
// Kernel 1: scores + rank + box transform (R12, proven).
// ---------------------------------------------------------------------------
__global__ __launch_bounds__(128) void segdet_topk_kernel(
    const float* __restrict__ pred_boxes,
    const float* __restrict__ pred_logits,
    const float* __restrict__ view,
    int*  __restrict__ ws_idx,
    int4* __restrict__ ws_box)
{
    const int b     = blockIdx.x >> 3;
    const int chunk = blockIdx.x & 7;
    const int tid   = threadIdx.x;

    __shared__ __align__(16) float sc[Q_];

    for (int q2 = tid; q2 < Q_; q2 += 128) {
        const float* l = pred_logits + (b * Q_ + q2) * NCLS_;
        float v[NCLS_];
        float m = -INFINITY;
        #pragma unroll
        for (int i = 0; i < NCLS_; ++i) { v[i] = l[i]; m = fmaxf(m, v[i]); }
        float s = 0.0f, e10 = -INFINITY;
        #pragma unroll
        for (int i = 0; i < NCLS_; ++i) {
            float e = expf(v[i] - m);
            s += e;
            if (i < NCLS_ - 1) e10 = fmaxf(e10, e);
        }
        sc[q2] = e10 / s;
    }
    __syncthreads();

    const int q = chunk * CHNK_ + tid;
    if (tid < CHNK_ && q < Q_) {
        const float my = sc[q];
        int rank = 0;
        #pragma unroll 4
        for (int j4 = 0; j4 < Q_ / 4; ++j4) {
            const float4 o = *(const float4*)&sc[j4 * 4];
            const int j = j4 * 4;
            rank += (o.x > my) || (o.x == my && (j + 0) < q);
            rank += (o.y > my) || (o.y == my && (j + 1) < q);
            rank += (o.z > my) || (o.z == my && (j + 2) < q);
            rank += (o.w > my) || (o.w == my && (j + 3) < q);
        }
        if (rank < NANC_) {
            const float* bx = pred_boxes + (b * Q_ + q) * 4;
            double cx = (double)bx[0], cy = (double)bx[1];
            double w  = exp((double)bx[2]);
            double h  = exp((double)bx[3]);
            double p[5] = { cx - 0.5 * w, cy - 0.5 * h,
                            cx + 0.5 * w, cy + 0.5 * h, 1.0 };
            const float* v5 = view + b * 25;
            int ico[4];
            #pragma unroll
            for (int i = 0; i < 4; ++i) {
                double acc = 0.0;
                #pragma unroll
                for (int j = 0; j < 5; ++j) acc += (double)v5[i * 5 + j] * p[j];
                ico[i] = (int)acc;                    // trunc == astype(int32)
            }
            int x0 = min(max(ico[0], 0), W_);
            int y0 = min(max(ico[1], 0), H_);
            int x1 = min(max(ico[2], 0), W_);
            int y1 = min(max(ico[3], 0), H_);
            const int slot = b * NANC_ + rank;
            ws_idx[slot] = q;
            ws_box[slot] = make_int4(x0, y0, x1, y1);
        }
    }
}

__device__ __forceinline__ void nt_store4(float* p, f32x4_ v) {
    __builtin_nontemporal_store(v, (f32x4_*)p);
}

__device__ __forceinline__ void gload_lds_16(const float* g, float* l) {
    __builtin_amdgcn_global_load_lds(
        (const __attribute__((address_space(1))) void*)g,
        (__attribute__((address_space(3))) void*)l,
        16, 0, 0);
}

// ---------------------------------------------------------------------------
// Kernel 2: BEV splat — fused R13 structure with a branch-free two-path walk.
// Entry word: q(10b) | rank<<10 (7b) | pix<<17 (8b) | sign<<31.
// Path A (nact <= FCAP_, ~87% of rows): ALL active features staged to LDS via
//   async global_load_lds (one barrier); walk reads features only from LDS ->
//   the loop has ZERO global reads => compiler emits no vmcnt waits and there
//   are ZERO mid-walk barriers. Pure NT-store stream + lgkm-only applies.
//   (R7's version of this kept a conditional global fallback in the loop,
//   which forced vmcnt waits on every event — this is why it regressed.)
// Path B (nact > FCAP_, central rows): R13 chunk-staged walk (LDS aliased).
// Event order identical to R4-R15 -> identical numerics.
// ---------------------------------------------------------------------------
__global__ __launch_bounds__(256) void segdet_bev_kernel(
    const float* __restrict__ box_feats,
    const int*   __restrict__ ws_idx,
    const int4*  __restrict__ ws_box,
    float* __restrict__ bev,
    float* __restrict__ mask)
{
    // center-out (LPT) row order
    const int hidx = blockIdx.x / B_;
    const int b    = blockIdx.x % B_;
    const int h    = (hidx & 1) ? (HHALF - 1 - (hidx >> 1)) : (HHALF + (hidx >> 1));

    const int tid = threadIdx.x;
    const int ln  = tid & 63;
    const int wv  = tid >> 6;

    __shared__ __align__(16) char s_mem[FCAP_ * C_ * 4];  // 59392 B (A: feats, B: chunk dbuf)
    __shared__ int s_box[NANC_];            // x0 | x1<<8 | q<<16
    __shared__ int s_nact;
    __shared__ int s_nopen[W_];
    __shared__ int s_ofs[W_ + 1];
    __shared__ int s_ent[2 * NANC_];
    __shared__ int s_wsum[4];

    float (*s_feat)[C_] = (float (*)[C_])s_mem;           // path A view
    float* s_chunkf     = (float*)s_mem;                  // path B view (2x16KB)

    // ---- wave-0 ballot compaction (deterministic k-order)
    if (tid < 64) {
        int na = 0;
        #pragma unroll
        for (int it = 0; it < 2; ++it) {
            int k = it * 64 + ln;
            bool act = false;
            int packed = 0;
            if (k < NANC_) {
                int4 bx = ws_box[b * NANC_ + k];
                int qi  = ws_idx[b * NANC_ + k];
                act = (bx.y <= h) && (h < bx.w) && (bx.x < bx.z);
                packed = bx.x | (bx.z << 8) | (qi << 16);
            }
            unsigned long long ball = __ballot(act);
            int pos = na + (int)__popcll(ball & ((1ull << ln) - 1ull));
            if (act) s_box[pos] = packed;
            na += (int)__popcll(ball);
        }
        if (ln == 0) s_nact = na;
    }
    __syncthreads();                                   // B1

    const int nact = s_nact;
    float* obase = bev + (size_t)(b * H_ + h) * W_ * C_ + ln * 4;
    float* mrow  = mask + (size_t)(b * H_ + h) * W_;

    // ---- empty-row fast path
    if (nact == 0) {
        const f32x4_ z = {0.f, 0.f, 0.f, 0.f};
        for (int w = wv; w < W_; w += 4)
            nt_store4(obase + (size_t)w * C_, z);
        if (tid < W_) __builtin_nontemporal_store(0.0f, &mrow[tid]);
        return;
    }

    // ---- per-pixel open/close counts + coverage (mask)
    int ntot = 0;
    if (tid < W_) {
        int nopen = 0, nclose = 0, cov = 0;
        for (int k = 0; k < nact; ++k) {
            int pk = s_box[k];
            int x0 = pk & 0xFF, x1 = (pk >> 8) & 0xFF;
            nopen  += (x0 == tid);
            nclose += (x1 == tid);
            cov    += (x0 <= tid) && (tid < x1);
        }
        s_nopen[tid] = nopen;
        ntot = nopen + nclose;
        __builtin_nontemporal_store((cov > 0) ? 1.0f : 0.0f, &mrow[tid]);
    }

    // ---- shuffle scan + cross-wave combine
    int incl = ntot;
    #pragma unroll
    for (int d = 1; d < 64; d <<= 1) {
        int u = __shfl_up(incl, d);
        incl = (ln >= d) ? incl + u : incl;
    }
    if (ln == 63) s_wsum[wv] = incl;
    __syncthreads();                                   // B2

    int prev = 0;
    #pragma unroll
    for (int j = 0; j < 4; ++j) prev += (j < wv) ? s_wsum[j] : 0;
    const int ne = s_wsum[0] + s_wsum[1] + s_wsum[2] + s_wsum[3];
    if (tid < W_) s_ofs[tid] = prev + incl - ntot;
    if (tid == 0) s_ofs[W_] = ne;
    __syncthreads();                                   // B3

    // ---- CSR entry scatter: ent = q | rank<<10 | pix<<17 | sign<<31 (k-order)
    if (tid < nact) {
        int pk = s_box[tid];
        int x0 = pk & 0xFF, x1 = (pk >> 8) & 0xFF, q = pk >> 16;
        int ro = 0, rc = 0;
        for (int j = 0; j < tid; ++j) {
            int pj = s_box[j];
            ro += ((pj & 0xFF) == x0);
            rc += (((pj >> 8) & 0xFF) == x1);
        }
        s_ent[s_ofs[x0] + ro] = q | (tid << 10) | (x0 << 17);
        if (x1 < W_)
            s_ent[s_ofs[x1] + s_nopen[x1] + rc] =
                (int)((unsigned)q | ((unsigned)tid << 10) |
                      ((unsigned)x1 << 17) | 0x80000000u);
    }
    __syncthreads();                                   // B4 (s_ent ready)

    const float* fbase = box_feats + (size_t)b * Q_ * C_ + ln * 4;

    if (nact <= FCAP_) {
        // ================= PATH A: all-LDS walk =================
        // stage all active features (async, one drain at the barrier)
        for (int k = wv; k < nact; k += 4) {
            const int q = s_box[k] >> 16;              // uniform LDS read
            gload_lds_16(fbase + (size_t)q * C_, &s_feat[k][0]);
        }
        __syncthreads();                               // staging complete

        f32x4_ acc = {0.f, 0.f, 0.f, 0.f};
        int cnt = 0;
        int w = wv;
        int entc = s_ent[0];                           // ne >= 1 here
        for (int e = 0; e < ne; ++e) {
            const int entn = (e + 1 < ne) ? s_ent[e + 1] : 0;  // prefetch
            const int pe = (entc >> 17) & 0xFF;
            for (; w < pe; w += 4)                     // pure NT-store stream
                nt_store4(obase + (size_t)w * C_, acc);
            const f32x4_ f =
                *(const f32x4_*)&s_feat[(entc >> 10) & 0x7F][ln * 4];  // lgkm only
            if (entc < 0) { acc -= f; --cnt; }
            else          { acc += f; ++cnt; }
            if (cnt == 0) acc = (f32x4_){0.f, 0.f, 0.f, 0.f};
            entc = entn;
        }
        for (; w < W_; w += 4)
            nt_store4(obase + (size_t)w * C_, acc);
    } else {
        // ================= PATH B: R13 chunk-staged walk =================
        const int nchunk = (ne + CHEV_ - 1) / CHEV_;

#define STAGE_(CI)                                                            \
    {                                                                         \
        const int base_ = (CI) * CHEV_;                                       \
        float* dst_ = s_chunkf + ((CI) & 1) * (CHEV_ * C_);                   \
        _Pragma("unroll")                                                     \
        for (int j = 0; j < 4; ++j) {                                         \
            const int e_ = base_ + wv * 4 + j;                                \
            if (e_ < ne) {                                                    \
                const int q_ = s_ent[e_] & 0x3FF;                             \
                gload_lds_16(fbase + (size_t)q_ * C_,                         \
                             dst_ + (wv * 4 + j) * C_);                       \
            }                                                                 \
        }                                                                     \
    }

        STAGE_(0);
        __syncthreads();

        f32x4_ acc = {0.f, 0.f, 0.f, 0.f};
        int cnt = 0;
        int w = wv;
        for (int ci = 0; ci < nchunk; ++ci) {
            if (ci + 1 < nchunk) STAGE_(ci + 1);
            const int ebeg = ci * CHEV_;
            const int eend = (ne < ebeg + CHEV_) ? ne : (ebeg + CHEV_);
            const float* cb = s_chunkf + (ci & 1) * (CHEV_ * C_);
            for (int e = ebeg; e < eend; ++e) {
                const int ent = s_ent[e];
                const int pe  = (ent >> 17) & 0xFF;
                for (; w < pe; w += 4)
                    nt_store4(obase + (size_t)w * C_, acc);
                const f32x4_ f = *(const f32x4_*)&cb[(e - ebeg) * C_ + ln * 4];
                if (ent < 0) { acc -= f; --cnt; }
                else         { acc += f; ++cnt; }
                if (cnt == 0) acc = (f32x4_){0.f, 0.f, 0.f, 0.f};
            }
            __syncthreads();
        }
#undef STAGE_
        for (; w < W_; w += 4)
            nt_store4(obase + (size_t)w * C_, acc);
    }
}

// ---------------------------------------------------------------------------
extern "C" void kernel_launch(void* const* d_in, const int* in_sizes, int n_in,
                              void* d_out, int out_size, void* d_ws, size_t ws_size,
                              hipStream_t stream) {
    const float* pred_boxes  = (const float*)d_in[0];
    const float* pred_logits = (const float*)d_in[1];
    const float* box_feats   = (const float*)d_in[2];
    const float* view        = (const float*)d_in[3];

    float* bev  = (float*)d_out;
    float* mask = bev + (size_t)B_ * H_ * W_ * C_;

    int*  ws_idx = (int*)d_ws;                            // 800 ints
    int4* ws_box = (int4*)((char*)d_ws + 3200);           // 800 int4 (16B aligned)

    segdet_topk_kernel<<<B_ * 8, 128, 0, stream>>>(pred_boxes, pred_logits, view,
                                                   ws_idx, ws_box);
    segdet_bev_kernel<<<B_ * H_, 256, 0, stream>>>(box_feats, ws_idx, ws_box,
                                                   bev, mask);
}

// Round 17
// 99.510 us; speedup vs baseline: 1.1923x; 1.0110x over previous
//
#include <hip/hip_runtime.h>
#include <math.h>

#define B_    8
#define Q_    900
#define NCLS_ 11
#define NANC_ 100
#define H_    200
#define W_    200
#define C_    256
#define HHALF 100
#define CHNK_ 113           // rank chunk per block in topk
#define CHEV_ 16            // events per staged chunk (path B)
#define FCAP_ 58            // all-LDS path capacity (58 KB feats)

typedef float f32x4_ __attribute__((ext_vector_type(4)));

// ---------------------------------------------------------------------------
// Kernel 1: scores + rank + box transform (R12, proven).
// ---------------------------------------------------------------------------
__global__ __launch_bounds__(128) void segdet_topk_kernel(
    const float* __restrict__ pred_boxes,
    const float* __restrict__ pred_logits,
    const float* __restrict__ view,
    int*  __restrict__ ws_idx,
    int4* __restrict__ ws_box)
{
    const int b     = blockIdx.x >> 3;
    const int chunk = blockIdx.x & 7;
    const int tid   = threadIdx.x;

    __shared__ __align__(16) float sc[Q_];

    for (int q2 = tid; q2 < Q_; q2 += 128) {
        const float* l = pred_logits + (b * Q_ + q2) * NCLS_;
        float v[NCLS_];
        float m = -INFINITY;
        #pragma unroll
        for (int i = 0; i < NCLS_; ++i) { v[i] = l[i]; m = fmaxf(m, v[i]); }
        float s = 0.0f, e10 = -INFINITY;
        #pragma unroll
        for (int i = 0; i < NCLS_; ++i) {
            float e = expf(v[i] - m);
            s += e;
            if (i < NCLS_ - 1) e10 = fmaxf(e10, e);
        }
        sc[q2] = e10 / s;
    }
    __syncthreads();

    const int q = chunk * CHNK_ + tid;
    if (tid < CHNK_ && q < Q_) {
        const float my = sc[q];
        int rank = 0;
        #pragma unroll 4
        for (int j4 = 0; j4 < Q_ / 4; ++j4) {
            const float4 o = *(const float4*)&sc[j4 * 4];
            const int j = j4 * 4;
            rank += (o.x > my) || (o.x == my && (j + 0) < q);
            rank += (o.y > my) || (o.y == my && (j + 1) < q);
            rank += (o.z > my) || (o.z == my && (j + 2) < q);
            rank += (o.w > my) || (o.w == my && (j + 3) < q);
        }
        if (rank < NANC_) {
            const float* bx = pred_boxes + (b * Q_ + q) * 4;
            double cx = (double)bx[0], cy = (double)bx[1];
            double w  = exp((double)bx[2]);
            double h  = exp((double)bx[3]);
            double p[5] = { cx - 0.5 * w, cy - 0.5 * h,
                            cx + 0.5 * w, cy + 0.5 * h, 1.0 };
            const float* v5 = view + b * 25;
            int ico[4];
            #pragma unroll
            for (int i = 0; i < 4; ++i) {
                double acc = 0.0;
                #pragma unroll
                for (int j = 0; j < 5; ++j) acc += (double)v5[i * 5 + j] * p[j];
                ico[i] = (int)acc;                    // trunc == astype(int32)
            }
            int x0 = min(max(ico[0], 0), W_);
            int y0 = min(max(ico[1], 0), H_);
            int x1 = min(max(ico[2], 0), W_);
            int y1 = min(max(ico[3], 0), H_);
            const int slot = b * NANC_ + rank;
            ws_idx[slot] = q;
            ws_box[slot] = make_int4(x0, y0, x1, y1);
        }
    }
}

__device__ __forceinline__ void nt_store4(float* p, f32x4_ v) {
    __builtin_nontemporal_store(v, (f32x4_*)p);
}

__device__ __forceinline__ void gload_lds_16(const float* g, float* l) {
    __builtin_amdgcn_global_load_lds(
        (const __attribute__((address_space(1))) void*)g,
        (__attribute__((address_space(3))) void*)l,
        16, 0, 0);
}

// ---------------------------------------------------------------------------
// Kernel 2: BEV splat — R16 two-path structure + DEPTH-2 PIPELINED feature
// reads (the one never-tried mechanism: every variant since R4 issued the
// event's feature read AT the event and consumed it immediately, exposing
// ~120cyc LDS / 200-900cyc global latency serially per event; heavy rows
// have ~120 events > 50 per-wave stores, so the walk is event-dominated).
// Named-register rotation (f0,f1,f2 / e0,e1,e2) — no runtime-indexed private
// arrays. Read values and apply order identical to R16 -> same numerics.
// ---------------------------------------------------------------------------
__global__ __launch_bounds__(256) void segdet_bev_kernel(
    const float* __restrict__ box_feats,
    const int*   __restrict__ ws_idx,
    const int4*  __restrict__ ws_box,
    float* __restrict__ bev,
    float* __restrict__ mask)
{
    // center-out (LPT) row order
    const int hidx = blockIdx.x / B_;
    const int b    = blockIdx.x % B_;
    const int h    = (hidx & 1) ? (HHALF - 1 - (hidx >> 1)) : (HHALF + (hidx >> 1));

    const int tid = threadIdx.x;
    const int ln  = tid & 63;
    const int wv  = tid >> 6;

    __shared__ __align__(16) char s_mem[FCAP_ * C_ * 4];  // A: feats, B: chunk dbuf
    __shared__ int s_box[NANC_];            // x0 | x1<<8 | q<<16
    __shared__ int s_nact;
    __shared__ int s_nopen[W_];
    __shared__ int s_ofs[W_ + 1];
    __shared__ int s_ent[2 * NANC_];
    __shared__ int s_wsum[4];

    float (*s_feat)[C_] = (float (*)[C_])s_mem;           // path A view
    float* s_chunkf     = (float*)s_mem;                  // path B view (2x16KB)

    // ---- wave-0 ballot compaction (deterministic k-order)
    if (tid < 64) {
        int na = 0;
        #pragma unroll
        for (int it = 0; it < 2; ++it) {
            int k = it * 64 + ln;
            bool act = false;
            int packed = 0;
            if (k < NANC_) {
                int4 bx = ws_box[b * NANC_ + k];
                int qi  = ws_idx[b * NANC_ + k];
                act = (bx.y <= h) && (h < bx.w) && (bx.x < bx.z);
                packed = bx.x | (bx.z << 8) | (qi << 16);
            }
            unsigned long long ball = __ballot(act);
            int pos = na + (int)__popcll(ball & ((1ull << ln) - 1ull));
            if (act) s_box[pos] = packed;
            na += (int)__popcll(ball);
        }
        if (ln == 0) s_nact = na;
    }
    __syncthreads();                                   // B1

    const int nact = s_nact;
    float* obase = bev + (size_t)(b * H_ + h) * W_ * C_ + ln * 4;
    float* mrow  = mask + (size_t)(b * H_ + h) * W_;

    // ---- empty-row fast path
    if (nact == 0) {
        const f32x4_ z = {0.f, 0.f, 0.f, 0.f};
        for (int w = wv; w < W_; w += 4)
            nt_store4(obase + (size_t)w * C_, z);
        if (tid < W_) __builtin_nontemporal_store(0.0f, &mrow[tid]);
        return;
    }

    // ---- per-pixel open/close counts + coverage (mask)
    int ntot = 0;
    if (tid < W_) {
        int nopen = 0, nclose = 0, cov = 0;
        for (int k = 0; k < nact; ++k) {
            int pk = s_box[k];
            int x0 = pk & 0xFF, x1 = (pk >> 8) & 0xFF;
            nopen  += (x0 == tid);
            nclose += (x1 == tid);
            cov    += (x0 <= tid) && (tid < x1);
        }
        s_nopen[tid] = nopen;
        ntot = nopen + nclose;
        __builtin_nontemporal_store((cov > 0) ? 1.0f : 0.0f, &mrow[tid]);
    }

    // ---- shuffle scan + cross-wave combine
    int incl = ntot;
    #pragma unroll
    for (int d = 1; d < 64; d <<= 1) {
        int u = __shfl_up(incl, d);
        incl = (ln >= d) ? incl + u : incl;
    }
    if (ln == 63) s_wsum[wv] = incl;
    __syncthreads();                                   // B2

    int prev = 0;
    #pragma unroll
    for (int j = 0; j < 4; ++j) prev += (j < wv) ? s_wsum[j] : 0;
    const int ne = s_wsum[0] + s_wsum[1] + s_wsum[2] + s_wsum[3];
    if (tid < W_) s_ofs[tid] = prev + incl - ntot;
    if (tid == 0) s_ofs[W_] = ne;
    __syncthreads();                                   // B3

    // ---- CSR entry scatter: ent = q | rank<<10 | pix<<17 | sign<<31 (k-order)
    if (tid < nact) {
        int pk = s_box[tid];
        int x0 = pk & 0xFF, x1 = (pk >> 8) & 0xFF, q = pk >> 16;
        int ro = 0, rc = 0;
        for (int j = 0; j < tid; ++j) {
            int pj = s_box[j];
            ro += ((pj & 0xFF) == x0);
            rc += (((pj >> 8) & 0xFF) == x1);
        }
        s_ent[s_ofs[x0] + ro] = q | (tid << 10) | (x0 << 17);
        if (x1 < W_)
            s_ent[s_ofs[x1] + s_nopen[x1] + rc] =
                (int)((unsigned)q | ((unsigned)tid << 10) |
                      ((unsigned)x1 << 17) | 0x80000000u);
    }
    __syncthreads();                                   // B4 (s_ent ready)

    const float* fbase = box_feats + (size_t)b * Q_ * C_ + ln * 4;

    if (nact <= FCAP_) {
        // ================= PATH A: all-LDS walk, depth-2 pipelined =========
        for (int k = wv; k < nact; k += 4) {
            const int q = s_box[k] >> 16;              // uniform LDS read
            gload_lds_16(fbase + (size_t)q * C_, &s_feat[k][0]);
        }
        __syncthreads();                               // staging complete

        f32x4_ acc = {0.f, 0.f, 0.f, 0.f};
        int cnt = 0;
        int w = wv;
        int e0 = s_ent[0];                             // ne >= 1 here
        int e1 = s_ent[(1 < ne) ? 1 : 0];
        f32x4_ f0 = *(const f32x4_*)&s_feat[(e0 >> 10) & 0x7F][ln * 4];
        f32x4_ f1 = *(const f32x4_*)&s_feat[(e1 >> 10) & 0x7F][ln * 4];
        for (int e = 0; e < ne; ++e) {
            // issue read for event e+2 now; its lgkm wait lands 2 iters later
            const int e2 = s_ent[(e + 2 < ne) ? (e + 2) : (ne - 1)];
            const f32x4_ f2 = *(const f32x4_*)&s_feat[(e2 >> 10) & 0x7F][ln * 4];
            const int pe = (e0 >> 17) & 0xFF;
            for (; w < pe; w += 4)                     // NT-store stream
                nt_store4(obase + (size_t)w * C_, acc);
            if (e0 < 0) { acc -= f0; --cnt; }
            else        { acc += f0; ++cnt; }
            if (cnt == 0) acc = (f32x4_){0.f, 0.f, 0.f, 0.f};
            e0 = e1; e1 = e2; f0 = f1; f1 = f2;        // named-reg rotation
        }
        for (; w < W_; w += 4)
            nt_store4(obase + (size_t)w * C_, acc);
    } else {
        // ================= PATH B: chunk-staged walk, depth-2 in-chunk =====
        const int nchunk = (ne + CHEV_ - 1) / CHEV_;

#define STAGE_(CI)                                                            \
    {                                                                         \
        const int base_ = (CI) * CHEV_;                                       \
        float* dst_ = s_chunkf + ((CI) & 1) * (CHEV_ * C_);                   \
        _Pragma("unroll")                                                     \
        for (int j = 0; j < 4; ++j) {                                         \
            const int e_ = base_ + wv * 4 + j;                                \
            if (e_ < ne) {                                                    \
                const int q_ = s_ent[e_] & 0x3FF;                             \
                gload_lds_16(fbase + (size_t)q_ * C_,                         \
                             dst_ + (wv * 4 + j) * C_);                       \
            }                                                                 \
        }                                                                     \
    }

        STAGE_(0);
        __syncthreads();

        f32x4_ acc = {0.f, 0.f, 0.f, 0.f};
        int cnt = 0;
        int w = wv;
        for (int ci = 0; ci < nchunk; ++ci) {
            if (ci + 1 < nchunk) STAGE_(ci + 1);
            const int ebeg = ci * CHEV_;
            const int eend = (ne < ebeg + CHEV_) ? ne : (ebeg + CHEV_);
            const float* cb = s_chunkf + (ci & 1) * (CHEV_ * C_);
            // depth-2 pipeline within the chunk (clamped at the boundary)
            int e0 = s_ent[ebeg];
            int e1 = s_ent[(ebeg + 1 < eend) ? (ebeg + 1) : (eend - 1)];
            f32x4_ f0 = *(const f32x4_*)&cb[0 * C_ + ln * 4];
            f32x4_ f1 = *(const f32x4_*)
                &cb[(size_t)(((ebeg + 1 < eend) ? (ebeg + 1) : (eend - 1)) - ebeg)
                    * C_ + ln * 4];
            for (int e = ebeg; e < eend; ++e) {
                const int i2 = (e + 2 < eend) ? (e + 2) : (eend - 1);
                const int e2 = s_ent[i2];
                const f32x4_ f2 = *(const f32x4_*)&cb[(size_t)(i2 - ebeg) * C_
                                                      + ln * 4];
                const int pe = (e0 >> 17) & 0xFF;
                for (; w < pe; w += 4)
                    nt_store4(obase + (size_t)w * C_, acc);
                if (e0 < 0) { acc -= f0; --cnt; }
                else        { acc += f0; ++cnt; }
                if (cnt == 0) acc = (f32x4_){0.f, 0.f, 0.f, 0.f};
                e0 = e1; e1 = e2; f0 = f1; f1 = f2;
            }
            __syncthreads();
        }
#undef STAGE_
        for (; w < W_; w += 4)
            nt_store4(obase + (size_t)w * C_, acc);
    }
}

// ---------------------------------------------------------------------------
extern "C" void kernel_launch(void* const* d_in, const int* in_sizes, int n_in,
                              void* d_out, int out_size, void* d_ws, size_t ws_size,
                              hipStream_t stream) {
    const float* pred_boxes  = (const float*)d_in[0];
    const float* pred_logits = (const float*)d_in[1];
    const float* box_feats   = (const float*)d_in[2];
    const float* view        = (const float*)d_in[3];

    float* bev  = (float*)d_out;
    float* mask = bev + (size_t)B_ * H_ * W_ * C_;

    int*  ws_idx = (int*)d_ws;                            // 800 ints
    int4* ws_box = (int4*)((char*)d_ws + 3200);           // 800 int4 (16B aligned)

    segdet_topk_kernel<<<B_ * 8, 128, 0, stream>>>(pred_boxes, pred_logits, view,
                                                   ws_idx, ws_box);
    segdet_bev_kernel<<<B_ * H_, 256, 0, stream>>>(box_feats, ws_idx, ws_box,
                                                   bev, mask);
}

// Round 18
// 98.629 us; speedup vs baseline: 1.2029x; 1.0089x over previous
//
#include <hip/hip_runtime.h>
#include <math.h>

#define B_    8
#define Q_    900
#define NCLS_ 11
#define NANC_ 100
#define H_    200
#define W_    200
#define C_    256
#define HHALF 100
#define CHNK_ 113           // rank chunk per block in topk
#define CHEV_ 16            // events per staged chunk (path B)
#define FCAP_ 58            // all-LDS path capacity (58 KB feats)
#define SPAN_ (W_ / 4)      // 50 contiguous pixels per wave

typedef float f32x4_ __attribute__((ext_vector_type(4)));

// ---------------------------------------------------------------------------
// Kernel 1: scores + rank + box transform (R12, proven).
// ---------------------------------------------------------------------------
__global__ __launch_bounds__(128) void segdet_topk_kernel(
    const float* __restrict__ pred_boxes,
    const float* __restrict__ pred_logits,
    const float* __restrict__ view,
    int*  __restrict__ ws_idx,
    int4* __restrict__ ws_box)
{
    const int b     = blockIdx.x >> 3;
    const int chunk = blockIdx.x & 7;
    const int tid   = threadIdx.x;

    __shared__ __align__(16) float sc[Q_];

    for (int q2 = tid; q2 < Q_; q2 += 128) {
        const float* l = pred_logits + (b * Q_ + q2) * NCLS_;
        float v[NCLS_];
        float m = -INFINITY;
        #pragma unroll
        for (int i = 0; i < NCLS_; ++i) { v[i] = l[i]; m = fmaxf(m, v[i]); }
        float s = 0.0f, e10 = -INFINITY;
        #pragma unroll
        for (int i = 0; i < NCLS_; ++i) {
            float e = expf(v[i] - m);
            s += e;
            if (i < NCLS_ - 1) e10 = fmaxf(e10, e);
        }
        sc[q2] = e10 / s;
    }
    __syncthreads();

    const int q = chunk * CHNK_ + tid;
    if (tid < CHNK_ && q < Q_) {
        const float my = sc[q];
        int rank = 0;
        #pragma unroll 4
        for (int j4 = 0; j4 < Q_ / 4; ++j4) {
            const float4 o = *(const float4*)&sc[j4 * 4];
            const int j = j4 * 4;
            rank += (o.x > my) || (o.x == my && (j + 0) < q);
            rank += (o.y > my) || (o.y == my && (j + 1) < q);
            rank += (o.z > my) || (o.z == my && (j + 2) < q);
            rank += (o.w > my) || (o.w == my && (j + 3) < q);
        }
        if (rank < NANC_) {
            const float* bx = pred_boxes + (b * Q_ + q) * 4;
            double cx = (double)bx[0], cy = (double)bx[1];
            double w  = exp((double)bx[2]);
            double h  = exp((double)bx[3]);
            double p[5] = { cx - 0.5 * w, cy - 0.5 * h,
                            cx + 0.5 * w, cy + 0.5 * h, 1.0 };
            const float* v5 = view + b * 25;
            int ico[4];
            #pragma unroll
            for (int i = 0; i < 4; ++i) {
                double acc = 0.0;
                #pragma unroll
                for (int j = 0; j < 5; ++j) acc += (double)v5[i * 5 + j] * p[j];
                ico[i] = (int)acc;                    // trunc == astype(int32)
            }
            int x0 = min(max(ico[0], 0), W_);
            int y0 = min(max(ico[1], 0), H_);
            int x1 = min(max(ico[2], 0), W_);
            int y1 = min(max(ico[3], 0), H_);
            const int slot = b * NANC_ + rank;
            ws_idx[slot] = q;
            ws_box[slot] = make_int4(x0, y0, x1, y1);
        }
    }
}

__device__ __forceinline__ void nt_store4(float* p, f32x4_ v) {
    __builtin_nontemporal_store(v, (f32x4_*)p);
}

__device__ __forceinline__ void gload_lds_16(const float* g, float* l) {
    __builtin_amdgcn_global_load_lds(
        (const __attribute__((address_space(1))) void*)g,
        (__attribute__((address_space(3))) void*)l,
        16, 0, 0);
}

// ---------------------------------------------------------------------------
// Kernel 2: BEV splat — R17 structure + CONTIGUOUS per-wave store spans.
// The one untested mechanism: R4-R17 waves emitted 1KB NT-stores at 4KB
// stride (w += 4); the 7TB/s fill kernel emits a sequential sweep. Here wave
// wv owns contiguous pixels [50wv, 50wv+50) -> 50KB sequential per wave,
// 200KB contiguous per block. All waves walk the full event list with the
// R17 depth-2 pipelined applies (pre-span events: stores naturally skipped;
// path A breaks once events pass span end). Stored value at each pixel is
// the same event-prefix sum in the same order -> identical numerics.
// ---------------------------------------------------------------------------
__global__ __launch_bounds__(256) void segdet_bev_kernel(
    const float* __restrict__ box_feats,
    const int*   __restrict__ ws_idx,
    const int4*  __restrict__ ws_box,
    float* __restrict__ bev,
    float* __restrict__ mask)
{
    // center-out (LPT) row order
    const int hidx = blockIdx.x / B_;
    const int b    = blockIdx.x % B_;
    const int h    = (hidx & 1) ? (HHALF - 1 - (hidx >> 1)) : (HHALF + (hidx >> 1));

    const int tid = threadIdx.x;
    const int ln  = tid & 63;
    const int wv  = tid >> 6;

    __shared__ __align__(16) char s_mem[FCAP_ * C_ * 4];  // A: feats, B: chunk dbuf
    __shared__ int s_box[NANC_];            // x0 | x1<<8 | q<<16
    __shared__ int s_nact;
    __shared__ int s_nopen[W_];
    __shared__ int s_ofs[W_ + 1];
    __shared__ int s_ent[2 * NANC_];
    __shared__ int s_wsum[4];

    float (*s_feat)[C_] = (float (*)[C_])s_mem;           // path A view
    float* s_chunkf     = (float*)s_mem;                  // path B view (2x16KB)

    // ---- wave-0 ballot compaction (deterministic k-order)
    if (tid < 64) {
        int na = 0;
        #pragma unroll
        for (int it = 0; it < 2; ++it) {
            int k = it * 64 + ln;
            bool act = false;
            int packed = 0;
            if (k < NANC_) {
                int4 bx = ws_box[b * NANC_ + k];
                int qi  = ws_idx[b * NANC_ + k];
                act = (bx.y <= h) && (h < bx.w) && (bx.x < bx.z);
                packed = bx.x | (bx.z << 8) | (qi << 16);
            }
            unsigned long long ball = __ballot(act);
            int pos = na + (int)__popcll(ball & ((1ull << ln) - 1ull));
            if (act) s_box[pos] = packed;
            na += (int)__popcll(ball);
        }
        if (ln == 0) s_nact = na;
    }
    __syncthreads();                                   // B1

    const int nact = s_nact;
    float* obase = bev + (size_t)(b * H_ + h) * W_ * C_ + ln * 4;
    float* mrow  = mask + (size_t)(b * H_ + h) * W_;

    const int span_lo = wv * SPAN_;
    const int span_hi = span_lo + SPAN_;

    // ---- empty-row fast path (contiguous spans)
    if (nact == 0) {
        const f32x4_ z = {0.f, 0.f, 0.f, 0.f};
        for (int w = span_lo; w < span_hi; ++w)
            nt_store4(obase + (size_t)w * C_, z);
        if (tid < W_) __builtin_nontemporal_store(0.0f, &mrow[tid]);
        return;
    }

    // ---- per-pixel open/close counts + coverage (mask)
    int ntot = 0;
    if (tid < W_) {
        int nopen = 0, nclose = 0, cov = 0;
        for (int k = 0; k < nact; ++k) {
            int pk = s_box[k];
            int x0 = pk & 0xFF, x1 = (pk >> 8) & 0xFF;
            nopen  += (x0 == tid);
            nclose += (x1 == tid);
            cov    += (x0 <= tid) && (tid < x1);
        }
        s_nopen[tid] = nopen;
        ntot = nopen + nclose;
        __builtin_nontemporal_store((cov > 0) ? 1.0f : 0.0f, &mrow[tid]);
    }

    // ---- shuffle scan + cross-wave combine
    int incl = ntot;
    #pragma unroll
    for (int d = 1; d < 64; d <<= 1) {
        int u = __shfl_up(incl, d);
        incl = (ln >= d) ? incl + u : incl;
    }
    if (ln == 63) s_wsum[wv] = incl;
    __syncthreads();                                   // B2

    int prev = 0;
    #pragma unroll
    for (int j = 0; j < 4; ++j) prev += (j < wv) ? s_wsum[j] : 0;
    const int ne = s_wsum[0] + s_wsum[1] + s_wsum[2] + s_wsum[3];
    if (tid < W_) s_ofs[tid] = prev + incl - ntot;
    if (tid == 0) s_ofs[W_] = ne;
    __syncthreads();                                   // B3

    // ---- CSR entry scatter: ent = q | rank<<10 | pix<<17 | sign<<31 (k-order)
    if (tid < nact) {
        int pk = s_box[tid];
        int x0 = pk & 0xFF, x1 = (pk >> 8) & 0xFF, q = pk >> 16;
        int ro = 0, rc = 0;
        for (int j = 0; j < tid; ++j) {
            int pj = s_box[j];
            ro += ((pj & 0xFF) == x0);
            rc += (((pj >> 8) & 0xFF) == x1);
        }
        s_ent[s_ofs[x0] + ro] = q | (tid << 10) | (x0 << 17);
        if (x1 < W_)
            s_ent[s_ofs[x1] + s_nopen[x1] + rc] =
                (int)((unsigned)q | ((unsigned)tid << 10) |
                      ((unsigned)x1 << 17) | 0x80000000u);
    }
    __syncthreads();                                   // B4 (s_ent ready)

    const float* fbase = box_feats + (size_t)b * Q_ * C_ + ln * 4;

    if (nact <= FCAP_) {
        // ========== PATH A: all-LDS, depth-2 pipelined, contiguous span =====
        for (int k = wv; k < nact; k += 4) {
            const int q = s_box[k] >> 16;              // uniform LDS read
            gload_lds_16(fbase + (size_t)q * C_, &s_feat[k][0]);
        }
        __syncthreads();                               // staging complete

        f32x4_ acc = {0.f, 0.f, 0.f, 0.f};
        int cnt = 0;
        int w = span_lo;
        int e0 = s_ent[0];                             // ne >= 1 here
        int e1 = s_ent[(1 < ne) ? 1 : 0];
        f32x4_ f0 = *(const f32x4_*)&s_feat[(e0 >> 10) & 0x7F][ln * 4];
        f32x4_ f1 = *(const f32x4_*)&s_feat[(e1 >> 10) & 0x7F][ln * 4];
        for (int e = 0; e < ne; ++e) {
            const int i2 = (e + 2 < ne) ? (e + 2) : (ne - 1);
            const int e2 = s_ent[i2];
            const f32x4_ f2 = *(const f32x4_*)&s_feat[(e2 >> 10) & 0x7F][ln * 4];
            const int pe_raw = (e0 >> 17) & 0xFF;
            const int pe = (pe_raw < span_hi) ? pe_raw : span_hi;
            for (; w < pe; ++w)                        // sequential NT stream
                nt_store4(obase + (size_t)w * C_, acc);
            if (pe_raw >= span_hi) break;              // span finished; acc done
            if (e0 < 0) { acc -= f0; --cnt; }
            else        { acc += f0; ++cnt; }
            if (cnt == 0) acc = (f32x4_){0.f, 0.f, 0.f, 0.f};
            e0 = e1; e1 = e2; f0 = f1; f1 = f2;        // named-reg rotation
        }
        for (; w < span_hi; ++w)
            nt_store4(obase + (size_t)w * C_, acc);
    } else {
        // ========== PATH B: chunk-staged, depth-2, contiguous span ==========
        const int nchunk = (ne + CHEV_ - 1) / CHEV_;

#define STAGE_(CI)                                                            \
    {                                                                         \
        const int base_ = (CI) * CHEV_;                                       \
        float* dst_ = s_chunkf + ((CI) & 1) * (CHEV_ * C_);                   \
        _Pragma("unroll")                                                     \
        for (int j = 0; j < 4; ++j) {                                         \
            const int e_ = base_ + wv * 4 + j;                                \
            if (e_ < ne) {                                                    \
                const int q_ = s_ent[e_] & 0x3FF;                             \
                gload_lds_16(fbase + (size_t)q_ * C_,                         \
                             dst_ + (wv * 4 + j) * C_);                       \
            }                                                                 \
        }                                                                     \
    }

        STAGE_(0);
        __syncthreads();

        f32x4_ acc = {0.f, 0.f, 0.f, 0.f};
        int cnt = 0;
        int w = span_lo;
        for (int ci = 0; ci < nchunk; ++ci) {
            if (ci + 1 < nchunk) STAGE_(ci + 1);
            const int ebeg = ci * CHEV_;
            const int eend = (ne < ebeg + CHEV_) ? ne : (ebeg + CHEV_);
            const float* cb = s_chunkf + (ci & 1) * (CHEV_ * C_);
            int e0 = s_ent[ebeg];
            int e1 = s_ent[(ebeg + 1 < eend) ? (ebeg + 1) : (eend - 1)];
            f32x4_ f0 = *(const f32x4_*)&cb[0 * C_ + ln * 4];
            f32x4_ f1 = *(const f32x4_*)
                &cb[(size_t)(((ebeg + 1 < eend) ? (ebeg + 1) : (eend - 1)) - ebeg)
                    * C_ + ln * 4];
            for (int e = ebeg; e < eend; ++e) {
                const int i2 = (e + 2 < eend) ? (e + 2) : (eend - 1);
                const int e2 = s_ent[i2];
                const f32x4_ f2 = *(const f32x4_*)&cb[(size_t)(i2 - ebeg) * C_
                                                      + ln * 4];
                const int pe_raw = (e0 >> 17) & 0xFF;
                const int pe = (pe_raw < span_hi) ? pe_raw : span_hi;
                for (; w < pe; ++w)                    // sequential NT stream
                    nt_store4(obase + (size_t)w * C_, acc);
                if (e0 < 0) { acc -= f0; --cnt; }      // no break (barriers)
                else        { acc += f0; ++cnt; }
                if (cnt == 0) acc = (f32x4_){0.f, 0.f, 0.f, 0.f};
                e0 = e1; e1 = e2; f0 = f1; f1 = f2;
            }
            __syncthreads();
        }
#undef STAGE_
        for (; w < span_hi; ++w)
            nt_store4(obase + (size_t)w * C_, acc);
    }
}

// ---------------------------------------------------------------------------
extern "C" void kernel_launch(void* const* d_in, const int* in_sizes, int n_in,
                              void* d_out, int out_size, void* d_ws, size_t ws_size,
                              hipStream_t stream) {
    const float* pred_boxes  = (const float*)d_in[0];
    const float* pred_logits = (const float*)d_in[1];
    const float* box_feats   = (const float*)d_in[2];
    const float* view        = (const float*)d_in[3];

    float* bev  = (float*)d_out;
    float* mask = bev + (size_t)B_ * H_ * W_ * C_;

    int*  ws_idx = (int*)d_ws;                            // 800 ints
    int4* ws_box = (int4*)((char*)d_ws + 3200);           // 800 int4 (16B aligned)

    segdet_topk_kernel<<<B_ * 8, 128, 0, stream>>>(pred_boxes, pred_logits, view,
                                                   ws_idx, ws_box);
    segdet_bev_kernel<<<B_ * H_, 256, 0, stream>>>(box_feats, ws_idx, ws_box,
                                                   bev, mask);
}